// Round 1
// baseline (316.675 us; speedup 1.0000x reference)
//
#include <hip/hip_runtime.h>
#include <math.h>

#define B 4
#define SEQ 8192
#define DIM 1024
#define HEADS 8
#define NCHUNK 256
#define LOG_NCHUNK 8
#define CLEN (SEQ / NCHUNK)      // 32 rows per chunk
#define GROUP 4                  // rows reduced per barrier
#define NGROUP (CLEN / GROUP)    // 8 groups
#define LN_EPS 1e-5f

typedef float vf4 __attribute__((ext_vector_type(4)));

// ---------------------------------------------------------------------------
// Pass 1: fused LayerNorm-stats + local EMA carry (zero initial state).
// Block = (b, chunk): 256 threads x float4 = all 1024 channels, CLEN rows.
// 4 rows are reduced per barrier: 8 interleaved shfl chains give ILP across
// the DS-pipe latency, barriers are amortized 4x, and the next 4-row group
// is prefetched before the reduction so 4 HBM loads stay in flight.
// 1024 blocks -> 4 blocks/CU (16 waves/CU) for latency hiding.
// ---------------------------------------------------------------------------
__global__ void __launch_bounds__(256) pass1_kernel(
        const float* __restrict__ x,
        const float* __restrict__ gamma,
        const float* __restrict__ beta,
        const float* __restrict__ alphas,
        float2* __restrict__ stats,
        float4* __restrict__ carry) {
    const int bid   = blockIdx.x;              // b*NCHUNK + chunk
    const int chunk = bid & (NCHUNK - 1);
    const int b     = bid >> LOG_NCHUNK;
    const int t     = threadIdx.x;
    const int c     = t * 4;
    const int h     = c >> 7;                  // 4 channels share one head
    const int wave  = t >> 6;
    const int lane  = t & 63;

    const float a   = 1.f / (1.f + expf(-alphas[h]));
    const float dec = 1.f - a;
    const float4 g  = *(const float4*)(gamma + c);
    const float4 be = *(const float4*)(beta + c);

    __shared__ float red[2][GROUP][8];         // [group parity][row][4 waves x {s,ss}]

    const int rowbase = b * SEQ + chunk * CLEN;
    const float4* xp = (const float4*)x + (long)rowbase * (DIM / 4) + t;

    float4 y = make_float4(0.f, 0.f, 0.f, 0.f);
    float4 xv[GROUP], xn[GROUP];
#pragma unroll
    for (int q = 0; q < GROUP; ++q) xv[q] = xp[q * (DIM / 4)];

    for (int gi = 0; gi < NGROUP; ++gi) {
        // prefetch next group before the reduction (clamped: redundant on last)
        const int nb = (gi + 1 < NGROUP) ? (gi + 1) * GROUP : gi * GROUP;
#pragma unroll
        for (int q = 0; q < GROUP; ++q) xn[q] = xp[(nb + q) * (DIM / 4)];

        float s[GROUP], ss[GROUP];
#pragma unroll
        for (int q = 0; q < GROUP; ++q) {
            s[q]  = xv[q].x + xv[q].y + xv[q].z + xv[q].w;
            ss[q] = xv[q].x * xv[q].x + xv[q].y * xv[q].y
                  + xv[q].z * xv[q].z + xv[q].w * xv[q].w;
        }
        // 8 independent reduction chains interleave across the DS pipe
#pragma unroll
        for (int off = 32; off > 0; off >>= 1) {
#pragma unroll
            for (int q = 0; q < GROUP; ++q) {
                s[q]  += __shfl_down(s[q], off);
                ss[q] += __shfl_down(ss[q], off);
            }
        }
        const int par = gi & 1;
        if (lane == 0) {
#pragma unroll
            for (int q = 0; q < GROUP; ++q) {
                red[par][q][wave]     = s[q];
                red[par][q][4 + wave] = ss[q];
            }
        }
        __syncthreads();
#pragma unroll
        for (int q = 0; q < GROUP; ++q) {
            const float S    = red[par][q][0] + red[par][q][1]
                             + red[par][q][2] + red[par][q][3];
            const float SS   = red[par][q][4] + red[par][q][5]
                             + red[par][q][6] + red[par][q][7];
            const float mean = S * (1.f / DIM);
            const float var  = SS * (1.f / DIM) - mean * mean;
            const float rstd = rsqrtf(var + LN_EPS);
            if (t == 0) stats[rowbase + gi * GROUP + q] = make_float2(mean, rstd);

            float4 u;
            u.x = (xv[q].x - mean) * rstd * g.x + be.x;
            u.y = (xv[q].y - mean) * rstd * g.y + be.y;
            u.z = (xv[q].z - mean) * rstd * g.z + be.z;
            u.w = (xv[q].w - mean) * rstd * g.w + be.w;
            y.x = dec * y.x + a * u.x;
            y.y = dec * y.y + a * u.y;
            y.z = dec * y.z + a * u.z;
            y.w = dec * y.w + a * u.w;
        }
#pragma unroll
        for (int q = 0; q < GROUP; ++q) xv[q] = xn[q];
    }
    carry[(long)bid * (DIM / 4) + t] = y;
}

// ---------------------------------------------------------------------------
// Pass 2 (tiny): serial scan of chunk carries per channel-pair.
// excl[k] = Y_{k-1};  Y_k = r^CLEN * Y_{k-1} + L_k.  r^32 via 5 squarings.
// 64-thread blocks -> 32 blocks spread over 32 CUs (was 16 blocks/16 CUs);
// unroll 16 batches 16 independent loads ahead of the serial FMA chain.
// ---------------------------------------------------------------------------
__global__ void __launch_bounds__(64) carry_scan_kernel(
        const float* __restrict__ alphas,
        const float2* __restrict__ carry,
        float2* __restrict__ excl) {
    const int tid = blockIdx.x * 64 + threadIdx.x;   // [0, B*DIM/2)
    const int cc  = tid & (DIM / 2 - 1);             // float2 index within row
    const int b   = tid >> 9;                        // DIM/2 == 512
    const int h   = (cc * 2) >> 7;

    const float a = 1.f / (1.f + expf(-alphas[h]));
    const float r = 1.f - a;
    float rn = r;                                    // r^32 = r squared 5 times
#pragma unroll
    for (int q = 0; q < 5; ++q) rn = rn * rn;        // CLEN == 32

    const float2* cp = carry + (long)b * NCHUNK * (DIM / 2) + cc;
    float2*       ep = excl  + (long)b * NCHUNK * (DIM / 2) + cc;

    float2 Y = make_float2(0.f, 0.f);
#pragma unroll 16
    for (int k = 0; k < NCHUNK; ++k) {
        const float2 loc = cp[(long)k * (DIM / 2)];
        ep[(long)k * (DIM / 2)] = Y;
        Y.x = rn * Y.x + loc.x;
        Y.y = rn * Y.y + loc.y;
    }
}

// ---------------------------------------------------------------------------
// Pass 3: final scan seeded with the true cross-chunk carry; writes out once.
// Row stats staged in LDS at block start (no global load on the loop's
// critical path). Nontemporal stores for `out` keep x resident in the 256 MB
// L3 so this pass's x re-read is mostly L3 hits instead of HBM.
// ---------------------------------------------------------------------------
__global__ void __launch_bounds__(256) pass2_kernel(
        const float* __restrict__ x,
        const float2* __restrict__ stats,
        const float* __restrict__ gamma,
        const float* __restrict__ beta,
        const float* __restrict__ alphas,
        const float* __restrict__ paramD,
        const float4* __restrict__ excl,
        float4* __restrict__ out) {
    const int bid   = blockIdx.x;              // b*NCHUNK + chunk
    const int chunk = bid & (NCHUNK - 1);
    const int b     = bid >> LOG_NCHUNK;
    const int t     = threadIdx.x;
    const int c     = t * 4;
    const int h     = c >> 7;

    const float a   = 1.f / (1.f + expf(-alphas[h]));
    const float dec = 1.f - a;
    const float4 g  = *(const float4*)(gamma  + c);
    const float4 be = *(const float4*)(beta   + c);
    const float4 D  = *(const float4*)(paramD + c);

    const int rowbase = b * SEQ + chunk * CLEN;
    const float4* xp = (const float4*)x + (long)rowbase * (DIM / 4) + t;
    float4*       op = (float4*)out     + (long)rowbase * (DIM / 4) + t;

    __shared__ float2 strow[CLEN];
    if (t < CLEN) strow[t] = stats[rowbase + t];

    float4 y = excl[(long)bid * (DIM / 4) + t];
    __syncthreads();

#pragma unroll 8
    for (int i = 0; i < CLEN; ++i) {
        const float2 st = strow[i];
        const float4 xv = xp[i * (DIM / 4)];
        float4 u, o;
        u.x = (xv.x - st.x) * st.y * g.x + be.x;
        u.y = (xv.y - st.x) * st.y * g.y + be.y;
        u.z = (xv.z - st.x) * st.y * g.z + be.z;
        u.w = (xv.w - st.x) * st.y * g.w + be.w;
        y.x = dec * y.x + a * u.x;
        y.y = dec * y.y + a * u.y;
        y.z = dec * y.z + a * u.z;
        y.w = dec * y.w + a * u.w;
        o.x = y.x + u.x * D.x;
        o.y = y.y + u.y * D.y;
        o.z = y.z + u.z * D.z;
        o.w = y.w + u.w * D.w;
        vf4 vo = { o.x, o.y, o.z, o.w };
        __builtin_nontemporal_store(vo, (vf4*)(op + i * (DIM / 4)));
    }
}

// ---------------------------------------------------------------------------
extern "C" void kernel_launch(void* const* d_in, const int* in_sizes, int n_in,
                              void* d_out, int out_size, void* d_ws, size_t ws_size,
                              hipStream_t stream) {
    const float* x      = (const float*)d_in[0];
    const float* gamma  = (const float*)d_in[1];
    const float* beta   = (const float*)d_in[2];
    const float* alphas = (const float*)d_in[3];
    const float* paramD = (const float*)d_in[4];
    float* out = (float*)d_out;

    char* ws = (char*)d_ws;
    float2* stats = (float2*)ws;                              // 256 KB (1<<18)
    float*  carry = (float*)(ws + (1 << 18));                 // 4 MB (1<<22)
    float*  excl  = (float*)(ws + (1 << 18) + (1 << 22));     // 4 MB

    pass1_kernel<<<B * NCHUNK, 256, 0, stream>>>(
        x, gamma, beta, alphas, stats, (float4*)carry);
    carry_scan_kernel<<<B * DIM / 2 / 64, 64, 0, stream>>>(
        alphas, (const float2*)carry, (float2*)excl);
    pass2_kernel<<<B * NCHUNK, 256, 0, stream>>>(
        x, stats, gamma, beta, alphas, paramD, (const float4*)excl, (float4*)out);
}

// Round 2
// 275.966 us; speedup vs baseline: 1.1475x; 1.1475x over previous
//
#include <hip/hip_runtime.h>
#include <math.h>

#define B 4
#define SEQ 8192
#define DIM 1024
#define HEADS 8
#define NCHUNK 256
#define LOG_NCHUNK 8
#define CLEN (SEQ / NCHUNK)      // 32 rows per chunk
#define LN_EPS 1e-5f

// ---------------------------------------------------------------------------
// Pass 1: fused LayerNorm-stats + local EMA carry, WAVE-PER-CHUNK.
// Each wave (64 lanes) owns one chunk; lane holds 16 channels as 4x float4
// at stride 256 floats (coalesced across lanes). LN reduction is a pure
// 6-level __shfl_xor inside the wave: NO LDS, NO barriers -> hipcc never
// force-drains vmcnt, so next-row loads pipeline under the reduce chain.
// Grid = B*NCHUNK/4 = 256 blocks of 4 waves (1 block/CU).
// ---------------------------------------------------------------------------
__global__ void __launch_bounds__(256) pass1_kernel(
        const float* __restrict__ x,
        const float* __restrict__ gamma,
        const float* __restrict__ beta,
        const float* __restrict__ alphas,
        float2* __restrict__ stats,
        float4* __restrict__ carry) {
    const int t     = threadIdx.x;
    const int wave  = t >> 6;
    const int lane  = t & 63;
    const int gcid  = blockIdx.x * 4 + wave;       // chunk id in [0, B*NCHUNK)
    const int chunk = gcid & (NCHUNK - 1);
    const int b     = gcid >> LOG_NCHUNK;

    // lane's channels: c_j = lane*4 + j*256  ->  head h_j = (lane>>5) + 2*j
    float a[4], dec[4];
    float4 g[4], be[4];
#pragma unroll
    for (int j = 0; j < 4; ++j) {
        const int h = (lane >> 5) + 2 * j;
        a[j]   = 1.f / (1.f + expf(-alphas[h]));
        dec[j] = 1.f - a[j];
        g[j]   = *(const float4*)(gamma + lane * 4 + j * 256);
        be[j]  = *(const float4*)(beta  + lane * 4 + j * 256);
    }

    const int rowbase = b * SEQ + chunk * CLEN;
    const float4* xp = (const float4*)x + (long)rowbase * (DIM / 4) + lane;

    float4 y[4];
#pragma unroll
    for (int j = 0; j < 4; ++j) y[j] = make_float4(0.f, 0.f, 0.f, 0.f);

    float4 xv[4];
#pragma unroll
    for (int j = 0; j < 4; ++j) xv[j] = xp[j * 64];

    for (int i = 0; i < CLEN; ++i) {
        // prefetch next row; no barrier anywhere, so these stay in flight
        const int ip = (i + 1 < CLEN) ? i + 1 : i;
        float4 xn[4];
#pragma unroll
        for (int j = 0; j < 4; ++j) xn[j] = xp[ip * 256 + j * 64];

        float s = 0.f, ss = 0.f;
#pragma unroll
        for (int j = 0; j < 4; ++j) {
            s  += xv[j].x + xv[j].y + xv[j].z + xv[j].w;
            ss += xv[j].x * xv[j].x + xv[j].y * xv[j].y
                + xv[j].z * xv[j].z + xv[j].w * xv[j].w;
        }
#pragma unroll
        for (int off = 32; off > 0; off >>= 1) {
            s  += __shfl_xor(s, off);
            ss += __shfl_xor(ss, off);
        }
        const float mean = s * (1.f / DIM);
        const float var  = ss * (1.f / DIM) - mean * mean;
        const float rstd = rsqrtf(var + LN_EPS);
        if (lane == 0) stats[rowbase + i] = make_float2(mean, rstd);

#pragma unroll
        for (int j = 0; j < 4; ++j) {
            float4 u;
            u.x = (xv[j].x - mean) * rstd * g[j].x + be[j].x;
            u.y = (xv[j].y - mean) * rstd * g[j].y + be[j].y;
            u.z = (xv[j].z - mean) * rstd * g[j].z + be[j].z;
            u.w = (xv[j].w - mean) * rstd * g[j].w + be[j].w;
            y[j].x = dec[j] * y[j].x + a[j] * u.x;
            y[j].y = dec[j] * y[j].y + a[j] * u.y;
            y[j].z = dec[j] * y[j].z + a[j] * u.z;
            y[j].w = dec[j] * y[j].w + a[j] * u.w;
            xv[j] = xn[j];
        }
    }
#pragma unroll
    for (int j = 0; j < 4; ++j)
        carry[(long)gcid * (DIM / 4) + lane + j * 64] = y[j];
}

// ---------------------------------------------------------------------------
// Pass 2 (tiny): serial scan of chunk carries per channel, IN-PLACE.
// Each thread owns one channel column: read carry[k], overwrite with the
// exclusive prefix, update. Halves scan traffic + workspace (no excl buf).
// 64 blocks x 64 threads -> spread across 64 CUs; unroll 16 batches loads.
// ---------------------------------------------------------------------------
__global__ void __launch_bounds__(64) carry_scan_kernel(
        const float* __restrict__ alphas,
        float* __restrict__ carry) {
    const int tid = blockIdx.x * 64 + threadIdx.x;   // [0, B*DIM)
    const int c   = tid & (DIM - 1);
    const int b   = tid >> 10;
    const int h   = c >> 7;

    const float a = 1.f / (1.f + expf(-alphas[h]));
    const float r = 1.f - a;
    float rn = r;                                    // r^32 = r squared 5 times
#pragma unroll
    for (int q = 0; q < 5; ++q) rn = rn * rn;        // CLEN == 32

    float* cp = carry + (long)b * NCHUNK * DIM + c;

    float Y = 0.f;
#pragma unroll 16
    for (int k = 0; k < NCHUNK; ++k) {
        const float loc = cp[(long)k * DIM];
        cp[(long)k * DIM] = Y;                       // exclusive prefix
        Y = rn * Y + loc;
    }
}

// ---------------------------------------------------------------------------
// Pass 3: final scan seeded with the true cross-chunk carry; writes out once.
// Same wave-per-chunk layout: no LDS, no barriers. Stats is a wave-uniform
// 8B broadcast load per row (1 transaction). Loop fully pipelines.
// ---------------------------------------------------------------------------
__global__ void __launch_bounds__(256) pass2_kernel(
        const float* __restrict__ x,
        const float2* __restrict__ stats,
        const float* __restrict__ gamma,
        const float* __restrict__ beta,
        const float* __restrict__ alphas,
        const float* __restrict__ paramD,
        const float4* __restrict__ excl,
        float4* __restrict__ out) {
    const int t     = threadIdx.x;
    const int wave  = t >> 6;
    const int lane  = t & 63;
    const int gcid  = blockIdx.x * 4 + wave;
    const int chunk = gcid & (NCHUNK - 1);
    const int b     = gcid >> LOG_NCHUNK;

    float a[4], dec[4];
    float4 g[4], be[4], D[4];
#pragma unroll
    for (int j = 0; j < 4; ++j) {
        const int h = (lane >> 5) + 2 * j;
        a[j]   = 1.f / (1.f + expf(-alphas[h]));
        dec[j] = 1.f - a[j];
        g[j]   = *(const float4*)(gamma  + lane * 4 + j * 256);
        be[j]  = *(const float4*)(beta   + lane * 4 + j * 256);
        D[j]   = *(const float4*)(paramD + lane * 4 + j * 256);
    }

    const int rowbase = b * SEQ + chunk * CLEN;
    const float4* xp = (const float4*)x + (long)rowbase * (DIM / 4) + lane;
    float4*       op = (float4*)out     + (long)rowbase * (DIM / 4) + lane;

    float4 y[4];
#pragma unroll
    for (int j = 0; j < 4; ++j)
        y[j] = excl[(long)gcid * (DIM / 4) + lane + j * 64];

#pragma unroll 4
    for (int i = 0; i < CLEN; ++i) {
        const float2 st = stats[rowbase + i];        // wave-uniform broadcast
#pragma unroll
        for (int j = 0; j < 4; ++j) {
            const float4 xv = xp[i * 256 + j * 64];
            float4 u, o;
            u.x = (xv.x - st.x) * st.y * g[j].x + be[j].x;
            u.y = (xv.y - st.x) * st.y * g[j].y + be[j].y;
            u.z = (xv.z - st.x) * st.y * g[j].z + be[j].z;
            u.w = (xv.w - st.x) * st.y * g[j].w + be[j].w;
            y[j].x = dec[j] * y[j].x + a[j] * u.x;
            y[j].y = dec[j] * y[j].y + a[j] * u.y;
            y[j].z = dec[j] * y[j].z + a[j] * u.z;
            y[j].w = dec[j] * y[j].w + a[j] * u.w;
            o.x = y[j].x + u.x * D[j].x;
            o.y = y[j].y + u.y * D[j].y;
            o.z = y[j].z + u.z * D[j].z;
            o.w = y[j].w + u.w * D[j].w;
            op[i * 256 + j * 64] = o;
        }
    }
}

// ---------------------------------------------------------------------------
extern "C" void kernel_launch(void* const* d_in, const int* in_sizes, int n_in,
                              void* d_out, int out_size, void* d_ws, size_t ws_size,
                              hipStream_t stream) {
    const float* x      = (const float*)d_in[0];
    const float* gamma  = (const float*)d_in[1];
    const float* beta   = (const float*)d_in[2];
    const float* alphas = (const float*)d_in[3];
    const float* paramD = (const float*)d_in[4];
    float* out = (float*)d_out;

    char* ws = (char*)d_ws;
    float2* stats = (float2*)ws;                     // 256 KB (1<<18)
    float*  carry = (float*)(ws + (1 << 18));        // 4 MB, scanned in place

    pass1_kernel<<<B * NCHUNK / 4, 256, 0, stream>>>(
        x, gamma, beta, alphas, stats, (float4*)carry);
    carry_scan_kernel<<<B * DIM / 64, 64, 0, stream>>>(alphas, carry);
    pass2_kernel<<<B * NCHUNK / 4, 256, 0, stream>>>(
        x, stats, gamma, beta, alphas, paramD, (const float4*)carry, (float4*)out);
}